// Round 1
// baseline (768.236 us; speedup 1.0000x reference)
//
#include <hip/hip_runtime.h>

#define N_NODES 50000
#define N_EDGES 800000
#define HDIM 128

typedef __bf16 bf16x8 __attribute__((ext_vector_type(8)));
typedef float f32x4 __attribute__((ext_vector_type(4)));

// round-to-nearest-even fp32 -> bf16 (inputs are finite; no NaN handling needed)
static __device__ __forceinline__ unsigned short f2bf(float f) {
    unsigned int u = __float_as_uint(f);
    u += 0x7fffu + ((u >> 16) & 1u);
    return (unsigned short)(u >> 16);
}

static __device__ __forceinline__ float silu_f(float x) {
    return x / (1.0f + __expf(-x));
}

// ---- convert weights to bf16, transposed: Wt[n][k] = W[k][n] ----
// W1t: [128][288] (K 265 zero-padded to 288), W2t: [128][128],
// N1t: [128][256], N2t: [128][128]
__global__ void conv_weights(const float* __restrict__ ew1, const float* __restrict__ ew2,
                             const float* __restrict__ nw1, const float* __restrict__ nw2,
                             unsigned short* __restrict__ W1t, unsigned short* __restrict__ W2t,
                             unsigned short* __restrict__ N1t, unsigned short* __restrict__ N2t) {
    int i = blockIdx.x * blockDim.x + threadIdx.x;
    if (i < 36864) {                       // 128*288
        int n = i / 288, k = i % 288;
        W1t[i] = (k < 265) ? f2bf(ew1[k * 128 + n]) : (unsigned short)0;
    } else if (i < 53248) {                // + 128*128
        int j = i - 36864;
        int n = j / 128, k = j % 128;
        W2t[j] = f2bf(ew2[k * 128 + n]);
    } else if (i < 86016) {                // + 128*256
        int j = i - 53248;
        int n = j / 256, k = j % 256;
        N1t[j] = f2bf(nw1[k * 128 + n]);
    } else if (i < 102400) {               // + 128*128
        int j = i - 86016;
        int n = j / 128, k = j % 128;
        N2t[j] = f2bf(nw2[k * 128 + n]);
    }
}

// ---- edge MLP + scatter-add ----
// 64 edges per workgroup; A tile [64 x 288] bf16 in LDS (stride 296);
// layer1 (K=288) -> silu -> LDS [64 x 128] (stride 136) -> layer2 (K=128)
// -> silu -> atomicAdd into agg[src], atomicAdd 1 into cnt[src].
__global__ __launch_bounds__(256, 4) void edge_kernel(
    const float* __restrict__ nf, const float* __restrict__ lattices,
    const float* __restrict__ frac_diff, const int* __restrict__ eidx,
    const int* __restrict__ e2g,
    const unsigned short* __restrict__ W1t, const float* __restrict__ b1,
    const unsigned short* __restrict__ W2t, const float* __restrict__ b2,
    float* __restrict__ agg, float* __restrict__ cnt) {
    constexpr int SA = 296;   // A row stride (elements); 296*2B=592B -> 2-way-free banks
    constexpr int S2 = 136;   // e-buffer row stride
    __shared__ unsigned short sm[64 * SA];

    const int tid = threadIdx.x;
    const int e0 = blockIdx.x * 64;

    // ---- build A tile: cols [0,128)=hi, [128,256)=hj, [256,262)=lat, [262,265)=fd, rest 0
    {
        const int m = tid >> 2;       // edge within tile
        const int q = tid & 3;        // quarter of the 128-wide halves
        const int e = e0 + m;
        const int src = eidx[e];
        const int dst = eidx[N_EDGES + e];
        unsigned short* row = sm + m * SA;
        const int cb = q * 32;
        const float4* hi4 = (const float4*)(nf + (size_t)src * HDIM) + q * 8;
        const float4* hj4 = (const float4*)(nf + (size_t)dst * HDIM) + q * 8;
#pragma unroll
        for (int j = 0; j < 8; ++j) {
            float4 v = hi4[j];
            *(ushort4*)(row + cb + 4 * j) =
                make_ushort4(f2bf(v.x), f2bf(v.y), f2bf(v.z), f2bf(v.w));
            float4 w = hj4[j];
            *(ushort4*)(row + HDIM + cb + 4 * j) =
                make_ushort4(f2bf(w.x), f2bf(w.y), f2bf(w.z), f2bf(w.w));
        }
        if (q == 0) {
            const int g = e2g[e];
#pragma unroll
            for (int j = 0; j < 6; ++j) row[256 + j] = f2bf(lattices[g * 6 + j]);
#pragma unroll
            for (int j = 0; j < 3; ++j) row[262 + j] = f2bf(frac_diff[e * 3 + j]);
#pragma unroll
            for (int j = 265; j < 288; ++j) row[j] = 0;
            atomicAdd(&cnt[src], 1.0f);
        }
    }
    __syncthreads();

    const int wave = tid >> 6;
    const int lane = tid & 63;
    const int lr = lane & 15;     // A row / B col / C col within 16-tile
    const int kq = lane >> 4;     // k-quad

    // ---- layer 1: wave handles rows [wave*16, wave*16+16), all 128 cols
    f32x4 acc[8] = {};
    const int arow = (wave * 16 + lr) * SA;
#pragma unroll
    for (int ks = 0; ks < 288; ks += 32) {
        bf16x8 a = *(const bf16x8*)(sm + arow + ks + kq * 8);
#pragma unroll
        for (int nt = 0; nt < 8; ++nt) {
            bf16x8 bb = *(const bf16x8*)(W1t + (nt * 16 + lr) * 288 + ks + kq * 8);
            acc[nt] = __builtin_amdgcn_mfma_f32_16x16x32_bf16(a, bb, acc[nt], 0, 0, 0);
        }
    }
    __syncthreads();   // everyone done reading A before overwrite

    // ---- silu + bias, write e to LDS bf16 (C layout: row=kq*4+r, col=lr)
#pragma unroll
    for (int nt = 0; nt < 8; ++nt) {
        const int col = nt * 16 + lr;
        const float bias = b1[col];
#pragma unroll
        for (int r = 0; r < 4; ++r) {
            const int m = wave * 16 + kq * 4 + r;
            sm[m * S2 + col] = f2bf(silu_f(acc[nt][r] + bias));
        }
    }
    __syncthreads();

    // ---- layer 2: K=128
    f32x4 acc2[8] = {};
    const int arow2 = (wave * 16 + lr) * S2;
#pragma unroll
    for (int ks = 0; ks < 128; ks += 32) {
        bf16x8 a = *(const bf16x8*)(sm + arow2 + ks + kq * 8);
#pragma unroll
        for (int nt = 0; nt < 8; ++nt) {
            bf16x8 bb = *(const bf16x8*)(W2t + (nt * 16 + lr) * 128 + ks + kq * 8);
            acc2[nt] = __builtin_amdgcn_mfma_f32_16x16x32_bf16(a, bb, acc2[nt], 0, 0, 0);
        }
    }

    // ---- epilogue: silu + atomic scatter-add onto agg[src]
    int srcs[4];
#pragma unroll
    for (int r = 0; r < 4; ++r) srcs[r] = eidx[e0 + wave * 16 + kq * 4 + r];
#pragma unroll
    for (int nt = 0; nt < 8; ++nt) {
        const int col = nt * 16 + lr;
        const float bias = b2[col];
#pragma unroll
        for (int r = 0; r < 4; ++r) {
            float v = silu_f(acc2[nt][r] + bias);
            atomicAdd(&agg[(size_t)srcs[r] * HDIM + col], v);
        }
    }
}

// ---- node MLP: h = concat(nf, agg/cnt) -> silu(h@N1+b1) -> silu(@N2+b2) + nf
__global__ __launch_bounds__(256, 4) void node_kernel(
    const float* __restrict__ nf, const float* __restrict__ agg,
    const float* __restrict__ cnt,
    const unsigned short* __restrict__ N1t, const float* __restrict__ b1,
    const unsigned short* __restrict__ N2t, const float* __restrict__ b2,
    float* __restrict__ out) {
    constexpr int SA = 264;   // 264*2B=528B -> 2-way-free banks
    constexpr int S2 = 136;
    __shared__ unsigned short sm[64 * SA];

    const int tid = threadIdx.x;
    const int n0 = blockIdx.x * 64;

    {
        const int m = tid >> 2;
        const int q = tid & 3;
        const int node = n0 + m;
        unsigned short* row = sm + m * SA;
        const int cb = q * 32;
        if (node < N_NODES) {
            const float inv = 1.0f / fmaxf(cnt[node], 1.0f);
            const float4* a4 = (const float4*)(nf + (size_t)node * HDIM) + q * 8;
            const float4* g4 = (const float4*)(agg + (size_t)node * HDIM) + q * 8;
#pragma unroll
            for (int j = 0; j < 8; ++j) {
                float4 v = a4[j];
                *(ushort4*)(row + cb + 4 * j) =
                    make_ushort4(f2bf(v.x), f2bf(v.y), f2bf(v.z), f2bf(v.w));
                float4 g = g4[j];
                *(ushort4*)(row + HDIM + cb + 4 * j) =
                    make_ushort4(f2bf(g.x * inv), f2bf(g.y * inv), f2bf(g.z * inv), f2bf(g.w * inv));
            }
        } else {
#pragma unroll
            for (int j = 0; j < 8; ++j) {
                *(ushort4*)(row + cb + 4 * j) = make_ushort4(0, 0, 0, 0);
                *(ushort4*)(row + HDIM + cb + 4 * j) = make_ushort4(0, 0, 0, 0);
            }
        }
    }
    __syncthreads();

    const int wave = tid >> 6;
    const int lane = tid & 63;
    const int lr = lane & 15;
    const int kq = lane >> 4;

    f32x4 acc[8] = {};
    const int arow = (wave * 16 + lr) * SA;
#pragma unroll
    for (int ks = 0; ks < 256; ks += 32) {
        bf16x8 a = *(const bf16x8*)(sm + arow + ks + kq * 8);
#pragma unroll
        for (int nt = 0; nt < 8; ++nt) {
            bf16x8 bb = *(const bf16x8*)(N1t + (nt * 16 + lr) * 256 + ks + kq * 8);
            acc[nt] = __builtin_amdgcn_mfma_f32_16x16x32_bf16(a, bb, acc[nt], 0, 0, 0);
        }
    }
    __syncthreads();

#pragma unroll
    for (int nt = 0; nt < 8; ++nt) {
        const int col = nt * 16 + lr;
        const float bias = b1[col];
#pragma unroll
        for (int r = 0; r < 4; ++r) {
            const int m = wave * 16 + kq * 4 + r;
            sm[m * S2 + col] = f2bf(silu_f(acc[nt][r] + bias));
        }
    }
    __syncthreads();

    f32x4 acc2[8] = {};
    const int arow2 = (wave * 16 + lr) * S2;
#pragma unroll
    for (int ks = 0; ks < 128; ks += 32) {
        bf16x8 a = *(const bf16x8*)(sm + arow2 + ks + kq * 8);
#pragma unroll
        for (int nt = 0; nt < 8; ++nt) {
            bf16x8 bb = *(const bf16x8*)(N2t + (nt * 16 + lr) * 128 + ks + kq * 8);
            acc2[nt] = __builtin_amdgcn_mfma_f32_16x16x32_bf16(a, bb, acc2[nt], 0, 0, 0);
        }
    }

#pragma unroll
    for (int nt = 0; nt < 8; ++nt) {
        const int col = nt * 16 + lr;
        const float bias = b2[col];
#pragma unroll
        for (int r = 0; r < 4; ++r) {
            const int node = n0 + wave * 16 + kq * 4 + r;
            if (node < N_NODES) {
                const size_t o = (size_t)node * HDIM + col;
                out[o] = nf[o] + silu_f(acc2[nt][r] + bias);
            }
        }
    }
}

extern "C" void kernel_launch(void* const* d_in, const int* in_sizes, int n_in,
                              void* d_out, int out_size, void* d_ws, size_t ws_size,
                              hipStream_t stream) {
    const float* node_features = (const float*)d_in[0];
    // d_in[1] frac_coords: unused by reference
    const float* lattices = (const float*)d_in[2];
    const float* frac_diff = (const float*)d_in[3];
    const int* edge_index = (const int*)d_in[4];
    const int* edge2graph = (const int*)d_in[5];
    const float* e_w1 = (const float*)d_in[6];
    const float* e_b1 = (const float*)d_in[7];
    const float* e_w2 = (const float*)d_in[8];
    const float* e_b2 = (const float*)d_in[9];
    const float* n_w1 = (const float*)d_in[10];
    const float* n_b1 = (const float*)d_in[11];
    const float* n_w2 = (const float*)d_in[12];
    const float* n_b2 = (const float*)d_in[13];

    // workspace layout (bytes):
    //   [0, 73728)            W1t  128x288 bf16
    //   [73728, 106496)       W2t  128x128 bf16
    //   [106496, 172032)      N1t  128x256 bf16
    //   [172032, 204800)      N2t  128x128 bf16
    //   [204800, 25804800)    agg  N*128 fp32
    //   [25804800, 26004800)  cnt  N fp32
    char* ws = (char*)d_ws;
    unsigned short* W1t = (unsigned short*)(ws);
    unsigned short* W2t = (unsigned short*)(ws + 73728);
    unsigned short* N1t = (unsigned short*)(ws + 106496);
    unsigned short* N2t = (unsigned short*)(ws + 172032);
    float* agg = (float*)(ws + 204800);
    float* cnt = (float*)(ws + 204800 + (size_t)N_NODES * HDIM * 4);

    // zero agg + cnt (ws is re-poisoned to 0xAA before every launch)
    hipMemsetAsync(ws + 204800, 0, (size_t)N_NODES * HDIM * 4 + (size_t)N_NODES * 4, stream);

    conv_weights<<<400, 256, 0, stream>>>(e_w1, e_w2, n_w1, n_w2, W1t, W2t, N1t, N2t);

    edge_kernel<<<N_EDGES / 64, 256, 0, stream>>>(
        node_features, lattices, frac_diff, edge_index, edge2graph,
        W1t, e_b1, W2t, e_b2, agg, cnt);

    node_kernel<<<(N_NODES + 63) / 64, 256, 0, stream>>>(
        node_features, agg, cnt, N1t, n_b1, N2t, n_b2, (float*)d_out);
}